// Round 15
// baseline (647.776 us; speedup 1.0000x reference)
//
#include <hip/hip_runtime.h>
#include <stdint.h>

#define CONF_T 0.01f
#define NMS_T  0.45f
#define M_TOP  200
#define TK_BS  512    // thr/sel block size (8 waves)
#define NMS_BS 256    // nms block size (4 waves)
#define FIN_BS 512
#define FS_BS  64     // fsel block size (1 wave; LDS-staged conf slab)
#define TCAP   2048   // bracket buffer capacity; overflow -> exact fallback
#define GCAP   256
#define KEYN1  0x407FFFFFu          // fkey(-1.0f)
#define BIN_N1 (KEYN1 >> 21)        // 0x203

typedef float float4u __attribute__((ext_vector_type(4), aligned(4)));

__device__ __forceinline__ uint32_t fkey(float f) {
    uint32_t u = __float_as_uint(f);
    return (u & 0x80000000u) ? ~u : (u | 0x80000000u);
}
__device__ __forceinline__ float fkey_inv(uint32_t k) {
    uint32_t u = (k & 0x80000000u) ? (k & 0x7FFFFFFFu) : ~k;
    return __uint_as_float(u);
}

// Parallel suffix-scan bin selection over nb bins (256 or multiple of 256).
// Scan work by threads 0..255; ALL block threads must reach the barriers.
__device__ __forceinline__ void suffix_select(
        uint32_t* hist, uint32_t* wsum, int nb, uint32_t pref, int shift,
        uint32_t wantv, uint32_t* s_prefix, uint32_t* s_want) {
    int tid = threadIdx.x;
    int lane = tid & 63, w = tid >> 6;
    int bpt = nb >> 8; if (bpt < 1) bpt = 1;
    int base = tid * bpt;
    uint32_t loc = 0, sfx = 0;
    if (tid < 256) {
        for (int j = 0; j < bpt; j++) loc += hist[base + j];
        sfx = loc;
        #pragma unroll
        for (int d = 1; d < 64; d <<= 1) {
            uint32_t y = __shfl_down(sfx, d);
            if (lane + d < 64) sfx += y;
        }
        if (lane == 0) wsum[w] = sfx;
    }
    __syncthreads();
    if (tid < 256) {
        uint32_t later = 0;
        for (int j = w + 1; j < 4; j++) later += wsum[j];
        uint32_t run = (sfx - loc) + later;
        for (int j = bpt - 1; j >= 0; j--) {
            uint32_t h = hist[base + j];
            uint32_t s2 = run + h;
            if (run < wantv && s2 >= wantv) {
                *s_prefix = pref | ((uint32_t)(base + j) << shift);
                *s_want   = wantv - run;
            }
            run = s2;
        }
    }
    __syncthreads();
}

// Dual-rank variant: boundary bins for TWO wants in one scan.
__device__ __forceinline__ void suffix_select2(
        uint32_t* hist, uint32_t* wsum, int nb, uint32_t want_a, uint32_t want_b,
        uint32_t* s_bin_a, uint32_t* s_bin_b) {
    int tid = threadIdx.x;
    int lane = tid & 63, w = tid >> 6;
    int bpt = nb >> 8;
    int base = tid * bpt;
    uint32_t loc = 0, sfx = 0;
    if (tid < 256) {
        for (int j = 0; j < bpt; j++) loc += hist[base + j];
        sfx = loc;
        #pragma unroll
        for (int d = 1; d < 64; d <<= 1) {
            uint32_t y = __shfl_down(sfx, d);
            if (lane + d < 64) sfx += y;
        }
        if (lane == 0) wsum[w] = sfx;
    }
    __syncthreads();
    if (tid < 256) {
        uint32_t later = 0;
        for (int j = w + 1; j < 4; j++) later += wsum[j];
        uint32_t run = (sfx - loc) + later;
        for (int j = bpt - 1; j >= 0; j--) {
            uint32_t h = hist[base + j];
            uint32_t s2 = run + h;
            if (run < want_a && s2 >= want_a) *s_bin_a = (uint32_t)(base + j);
            if (run < want_b && s2 >= want_b) *s_bin_b = (uint32_t)(base + j);
            run = s2;
        }
    }
    __syncthreads();
}

__device__ __forceinline__ float4 decode_box(float4 l, float4 d) {
    float cx = d.x + (l.x * 0.1f) * d.z;
    float cy = d.y + (l.y * 0.1f) * d.w;
    float w  = d.z * expf(l.z * 0.2f);
    float h  = d.w * expf(l.w * 0.2f);
    float x1 = cx - w * 0.5f, y1 = cy - h * 0.5f;
    float x2 = x1 + w, y2 = y1 + h;
    float4 o;
    o.x = fminf(fmaxf(x1, 0.f), 1.f);
    o.y = fminf(fmaxf(y1, 0.f), 1.f);
    o.z = fminf(fmaxf(x2, 0.f), 1.f);
    o.w = fminf(fmaxf(y2, 0.f), 1.f);
    return o;
}

// Streaming softmax m,s with arithmetic order IDENTICAL to the original
// softmax_kernel (max over c=0..80 in order; sum of expf in order).
__device__ __forceinline__ void softmax_ms(const float* __restrict__ p,
                                           float& m_out, float& s_out) {
    float m;
    {
        float4u f = *(const float4u*)p;
        m = f.x; m = fmaxf(m, f.y); m = fmaxf(m, f.z); m = fmaxf(m, f.w);
        #pragma unroll
        for (int i = 1; i < 20; i++) {
            float4u g = *(const float4u*)(p + 4 * i);
            m = fmaxf(m, g.x); m = fmaxf(m, g.y); m = fmaxf(m, g.z); m = fmaxf(m, g.w);
        }
        m = fmaxf(m, p[80]);
    }
    float s = 0.f;
    #pragma unroll
    for (int i = 0; i < 20; i++) {
        float4u g = *(const float4u*)(p + 4 * i);
        s += expf(g.x - m); s += expf(g.y - m); s += expf(g.z - m); s += expf(g.w - m);
    }
    s += expf(p[80] - m);
    m_out = m; s_out = s;
}

// ---------------- fast path A: softmax of the 2048 sampled anchors ------------------
__global__ __launch_bounds__(256) void samp_kernel(
        const float* __restrict__ conf, float* __restrict__ samp, int N, int Cm1) {
    int b = blockIdx.x >> 3;
    int t = ((blockIdx.x & 7) << 8) + threadIdx.x;     // 0..2047
    int n = (t >> 9) * (N >> 2) + (t & 511);           // same sample set as old code
    const float* p = conf + ((size_t)b * N + n) * 81;
    float m, s; softmax_ms(p, m, s);
    float* ob = samp + ((size_t)b * Cm1) * 2048 + t;
    #pragma unroll
    for (int i = 0; i < 20; i++) {
        float4u g = *(const float4u*)(p + 4 * i);
        float e4[4] = { g.x, g.y, g.z, g.w };
        #pragma unroll
        for (int j = 0; j < 4; j++) {
            int c = 4 * i + j;
            if (c >= 1) ob[(size_t)(c - 1) * 2048] = expf(e4[j] - m) / s;
        }
    }
    ob[(size_t)(Cm1 - 1) * 2048] = expf(p[80] - m) / s;
}

// ---------------- fast path B: per-row bracket thresholds + counter init ------------
__global__ __launch_bounds__(TK_BS) void thr_kernel(
        const float* __restrict__ samp, float* __restrict__ thrLo,
        float* __restrict__ thrHi, uint32_t* __restrict__ gcnt,
        uint32_t* __restrict__ tcnt, int* __restrict__ pcnt, int Cm1) {
    __shared__ uint32_t hist[2048];
    __shared__ uint32_t wsum[4];
    __shared__ uint32_t s_bin_a, s_bin_b;
    int row = blockIdx.x, tid = threadIdx.x;
    const float* sp = samp + ((size_t)row << 11);
    for (int i = tid; i < 2048; i += TK_BS) hist[i] = 0;
    __syncthreads();
    for (int i = tid; i < 2048; i += TK_BS) {
        float f = sp[i];
        atomicAdd(&hist[fkey(f > CONF_T ? f : -1.0f) >> 21], 1u);
    }
    __syncthreads();
    suffix_select2(hist, wsum, 2048, 3u, 25u, &s_bin_a, &s_bin_b);
    if (tid == 0) {
        uint32_t h = s_bin_a, l = s_bin_b;
        uint32_t hi_key = ((h + 1) << 21) - 1u;        // h=2047 wraps -> NaN -> G=0
        uint32_t lo_key = (l << 21) - 1u;
        float hiF = fkey_inv(hi_key);
        float loF = fmaxf(fkey_inv(lo_key), CONF_T);
        bool rok = (l > BIN_N1);
        thrLo[row] = rok ? loF : __uint_as_float(0x7F800000u);   // +inf => fallback
        thrHi[row] = hiF;
        gcnt[row] = 0; tcnt[row] = 0;
        if ((row % Cm1) == 0) pcnt[row / Cm1] = 0;
    }
}

// ---------------- fast path C: LDS-staged softmax + threshold scatter ---------------
// Stage the 64-anchor x 81-logit conf slab into LDS (compiler can't rematerialize
// LDS), then per thread: m (seq fmax), s (seq expf sum), exact expf(x-m)/s filter —
// all arithmetic in reference order => bit-identical.
__global__ __launch_bounds__(FS_BS) void fsel_kernel(
        const float* __restrict__ conf,
        const float* __restrict__ thrLo, const float* __restrict__ thrHi,
        float* __restrict__ gval, int* __restrict__ gidx, uint32_t* __restrict__ gcnt,
        uint32_t* __restrict__ tkey, int* __restrict__ tixg, uint32_t* __restrict__ tcnt,
        int N, int Cm1) {
    __shared__ float xs[FS_BS * 81];                   // 20736 B
    __shared__ float s_lo[128], s_hi[128];
    int tid = threadIdx.x;
    int nb = N >> 6;
    int b = blockIdx.x / nb;
    int n0 = (blockIdx.x % nb) << 6;
    for (int c = tid; c < Cm1; c += FS_BS) {
        s_lo[c] = thrLo[b * Cm1 + c];                  // +inf on fallback rows
        s_hi[c] = thrHi[b * Cm1 + c];
    }
    // coalesced float4 stage: slab start offset is 16B-aligned (n0*81*4 % 16 == 0)
    const float4* g4 = (const float4*)(conf + ((size_t)b * N + n0) * 81);
    float4* l4 = (float4*)xs;
    #pragma unroll 4
    for (int k = tid; k < (FS_BS * 81 / 4); k += FS_BS) l4[k] = g4[k];
    __syncthreads();

    const float* row = xs + tid * 81;                  // odd word stride: <=2-way bank alias
    float m = row[0];
    for (int c = 1; c < 81; c++) m = fmaxf(m, row[c]);
    float s = 0.f;
    for (int c = 0; c < 81; c++) s += expf(row[c] - m);

    int n = n0 + tid;
    int lane = tid;                                    // block == one wave
    uint64_t lowerm = (lane == 0) ? 0ull : (~0ull >> (64 - lane));
    int rowb = b * Cm1;

    for (int c = 1; c < 81; c++) {
        float fv = expf(row[c] - m) / s;               // identical arithmetic to reference
        bool ex = fv > s_lo[c - 1];
        uint64_t mex = __ballot(ex);
        if (mex == 0) continue;
        bool hb = ex && (fv > s_hi[c - 1]);
        uint64_t mhi = __ballot(hb);
        uint64_t mlo = mex & ~mhi;
        int orow = rowb + (c - 1);
        if (mhi) {
            int src = (int)__ffsll((unsigned long long)mhi) - 1;
            uint32_t bse = 0;
            if (lane == src) bse = atomicAdd(&gcnt[orow], (uint32_t)__popcll(mhi));
            bse = (uint32_t)__shfl((int)bse, src);
            if (hb) {
                uint32_t pp = bse + (uint32_t)__popcll(mhi & lowerm);
                if (pp < GCAP) {
                    gval[(size_t)orow * GCAP + pp] = fv;
                    gidx[(size_t)orow * GCAP + pp] = n;
                }
            }
        }
        if (mlo) {
            int src = (int)__ffsll((unsigned long long)mlo) - 1;
            uint32_t bse = 0;
            if (lane == src) bse = atomicAdd(&tcnt[orow], (uint32_t)__popcll(mlo));
            bse = (uint32_t)__shfl((int)bse, src);
            if (ex && !hb) {
                uint32_t pp = bse + (uint32_t)__popcll(mlo & lowerm);
                if (pp < TCAP) {
                    tkey[(size_t)orow * TCAP + pp] = fkey(fv);
                    tixg[(size_t)orow * TCAP + pp] = n;
                }
            }
        }
    }
}

// ---------------- fast path D: finish selection -> rank-ordered (val,idx) -----------
__global__ __launch_bounds__(FIN_BS) void fin_kernel(
        const float* __restrict__ conf,
        const float* __restrict__ thrLo,
        const float* __restrict__ gval, const int* __restrict__ gidx,
        const uint32_t* __restrict__ gcnt,
        const uint32_t* __restrict__ tkeyg, const int* __restrict__ tixg2,
        const uint32_t* __restrict__ tcntg,
        float* __restrict__ tval, int* __restrict__ tidx,
        int N, int Cm1) {
    __shared__ __align__(16) uint32_t hist[2048];
    __shared__ __align__(16) uint32_t tk[TCAP];        // reused as e_pack (256 u64)
    __shared__ int      tix[TCAP];
    __shared__ uint32_t wsum[4];
    __shared__ uint32_t s_prefix, s_want;
    __shared__ uint32_t ngt, ntie, tcs;
    __shared__ float    e_val[256];
    __shared__ int      e_idx[256];
    __shared__ int      tiebuf[256];

    int row = blockIdx.x, tid = threadIdx.x;
    int b = row / Cm1, cls = (row % Cm1) + 1;
    uint32_t G = gcnt[row], T = tcntg[row];
    bool ok = (thrLo[row] < 2.0f) && (G <= (uint32_t)M_TOP) &&
              (T <= (uint32_t)TCAP) && (G + T >= (uint32_t)M_TOP);

    if (tid < 256) { e_val[tid] = -1.0f; e_idx[tid] = tid; }
    if (tid == 0) { ngt = 0; ntie = 0; tcs = 0; }
    __syncthreads();

    uint32_t kth = KEYN1, rfin = 0;
    if (ok) {
        if (tid < (int)G) {                            // G <= 200
            e_val[tid] = gval[(size_t)row * GCAP + tid];
            e_idx[tid] = gidx[(size_t)row * GCAP + tid];
        }
        for (int i = tid; i < (int)T; i += FIN_BS) {
            tk[i]  = tkeyg[(size_t)row * TCAP + i];
            tix[i] = tixg2[(size_t)row * TCAP + i];
        }
        if (tid == 0) ngt = G;
        __syncthreads();
        uint32_t want_t = (uint32_t)M_TOP - G;
        if (want_t > 0) {
            for (int i = tid; i < 2048; i += FIN_BS) hist[i] = 0;
            __syncthreads();
            for (int i = tid; i < (int)T; i += FIN_BS) atomicAdd(&hist[tk[i] >> 21], 1u);
            __syncthreads();
            suffix_select(hist, wsum, 2048, 0u, 21, want_t, &s_prefix, &s_want);
            uint32_t pre0 = s_prefix, w0 = s_want;
            uint32_t bb0 = pre0 >> 21;
            for (int i = tid; i < 2048; i += FIN_BS) hist[i] = 0;
            __syncthreads();
            for (int i = tid; i < (int)T; i += FIN_BS)
                if ((tk[i] >> 21) == bb0) atomicAdd(&hist[(tk[i] >> 10) & 2047u], 1u);
            __syncthreads();
            suffix_select(hist, wsum, 2048, pre0, 10, w0, &s_prefix, &s_want);
            uint32_t pre1 = s_prefix, w1 = s_want;
            for (int i = tid; i < 1024; i += FIN_BS) hist[i] = 0;
            __syncthreads();
            for (int i = tid; i < (int)T; i += FIN_BS)
                if ((tk[i] >> 10) == (pre1 >> 10)) atomicAdd(&hist[tk[i] & 1023u], 1u);
            __syncthreads();
            suffix_select(hist, wsum, 1024, pre1, 0, w1, &s_prefix, &s_want);
            kth = s_prefix; rfin = s_want;
            for (int i = tid; i < (int)T; i += FIN_BS) {
                uint32_t k = tk[i];
                if (k > kth) {
                    uint32_t pq = atomicAdd(&ngt, 1u);
                    if (pq < 256) { e_val[pq] = fkey_inv(k); e_idx[pq] = tix[i]; }
                } else if (k == kth) {
                    uint32_t pq = atomicAdd(&ntie, 1u);
                    if (pq < 256) tiebuf[pq] = tix[i];
                }
            }
            __syncthreads();
        }
    } else {
        // exact fallback: recompute probs from conf (identical arithmetic); slow, rare
        auto probf = [&](int i) -> float {
            const float* pp = conf + ((size_t)b * N + i) * 81;
            float mm, ss; softmax_ms(pp, mm, ss);
            return expf(pp[cls] - mm) / ss;
        };
        for (int i = tid; i < 2048; i += FIN_BS) hist[i] = 0;
        __syncthreads();
        for (int i = tid; i < N; i += FIN_BS) {
            float f = probf(i);
            atomicAdd(&hist[fkey(f > CONF_T ? f : -1.0f) >> 21], 1u);
        }
        __syncthreads();
        suffix_select(hist, wsum, 2048, 0u, 21, (uint32_t)M_TOP, &s_prefix, &s_want);
        uint32_t b0 = s_prefix >> 21;
        uint32_t want1 = s_want;
        bool collect = (b0 != BIN_N1);
        for (int i = tid; i < N; i += FIN_BS) {
            float f = probf(i);
            float mv = f > CONF_T ? f : -1.0f;
            uint32_t k = fkey(mv);
            uint32_t bin = k >> 21;
            if (bin > b0) {
                uint32_t pq = atomicAdd(&ngt, 1u);
                if (pq < 256) { e_val[pq] = mv; e_idx[pq] = i; }
            } else if (bin == b0 && collect) {
                uint32_t pq = atomicAdd(&tcs, 1u);
                if (pq < TCAP) { tk[pq] = k; tix[pq] = i; }
            }
        }
        __syncthreads();
        if (collect && tcs <= TCAP) {
            int Tl = (int)tcs;
            for (int i = tid; i < 2048; i += FIN_BS) hist[i] = 0;
            __syncthreads();
            for (int i = tid; i < Tl; i += FIN_BS) atomicAdd(&hist[(tk[i] >> 10) & 2047u], 1u);
            __syncthreads();
            suffix_select(hist, wsum, 2048, b0 << 21, 10, want1, &s_prefix, &s_want);
            uint32_t pre2 = s_prefix, want2 = s_want;
            uint32_t b1 = (pre2 >> 10) & 2047u;
            for (int i = tid; i < 1024; i += FIN_BS) hist[i] = 0;
            __syncthreads();
            for (int i = tid; i < Tl; i += FIN_BS)
                if (((tk[i] >> 10) & 2047u) == b1) atomicAdd(&hist[tk[i] & 1023u], 1u);
            __syncthreads();
            suffix_select(hist, wsum, 1024, pre2, 0, want2, &s_prefix, &s_want);
            kth = s_prefix; rfin = s_want;
            for (int i = tid; i < Tl; i += FIN_BS) {
                uint32_t k = tk[i];
                if (k > kth) {
                    uint32_t pq = atomicAdd(&ngt, 1u);
                    if (pq < 256) { e_val[pq] = fkey_inv(k); e_idx[pq] = tix[i]; }
                } else if (k == kth) {
                    uint32_t pq = atomicAdd(&ntie, 1u);
                    if (pq < 256) tiebuf[pq] = tix[i];
                }
            }
            __syncthreads();
        } else if (collect) {
            const int shifts[2] = {10, 0};
            const int nbins_[2] = {2048, 1024};
            if (tid == 0) { s_prefix = b0 << 21; s_want = want1; }
            __syncthreads();
            for (int lev = 0; lev < 2; lev++) {
                int shift = shifts[lev];
                int nbv = nbins_[lev];
                uint32_t bmask = (uint32_t)nbv - 1u;
                uint32_t pref = s_prefix, wantv = s_want;
                uint32_t pmask = 0xFFFFFFFFu << (shift + ((nbv == 2048) ? 11 : 10));
                for (int i = tid; i < nbv; i += FIN_BS) hist[i] = 0;
                __syncthreads();
                for (int i = tid; i < N; i += FIN_BS) {
                    float f = probf(i);
                    uint32_t k = fkey(f > CONF_T ? f : -1.0f);
                    if ((k & pmask) == (pref & pmask)) atomicAdd(&hist[(k >> shift) & bmask], 1u);
                }
                __syncthreads();
                suffix_select(hist, wsum, nbv, pref, shift, wantv, &s_prefix, &s_want);
            }
            kth = s_prefix; rfin = s_want;
            for (int i = tid; i < N; i += FIN_BS) {
                float f = probf(i);
                float mv = f > CONF_T ? f : -1.0f;
                uint32_t k = fkey(mv);
                if ((k >> 21) == b0) {
                    if (k > kth) {
                        uint32_t pq = atomicAdd(&ngt, 1u);
                        if (pq < 256) { e_val[pq] = mv; e_idx[pq] = i; }
                    } else if (k == kth) {
                        uint32_t pq = atomicAdd(&ntie, 1u);
                        if (pq < 256) tiebuf[pq] = i;
                    }
                }
            }
            __syncthreads();
        }
    }

    // ---- ties, rank order (packed u64 keys) -> rank-ordered (val,idx) to global ----
    uint32_t gcount = min(ngt, (uint32_t)M_TOP);
    uint32_t nt = min(ntie, 256u);
    if (tid < (int)nt) {
        int mine = tiebuf[tid];
        uint32_t rk = 0;
        for (uint32_t j = 0; j < nt; j++) if (tiebuf[j] < mine) rk++;
        if (rk < rfin) {
            uint32_t slot = gcount + rk;
            if (slot < M_TOP) { e_val[slot] = fkey_inv(kth); e_idx[slot] = mine; }
        }
    }
    __syncthreads();
    uint64_t* e_pack = (uint64_t*)tk;
    if (tid < 256)
        e_pack[tid] = ((uint64_t)fkey(e_val[tid]) << 32) | (uint32_t)~(uint32_t)e_idx[tid];
    __syncthreads();
    if (tid < M_TOP) {
        uint64_t mine = e_pack[tid];
        uint32_t rk = 0;
        for (int j = 0; j < M_TOP; j++) rk += (e_pack[j] > mine) ? 1u : 0u;
        tval[(size_t)row * M_TOP + rk] = e_val[tid];
        tidx[(size_t)row * M_TOP + rk] = e_idx[tid];
    }
}

// ---------------- generic-N path: softmax + transpose (kept for N not mult. 256) ----
__global__ __launch_bounds__(256, 4) void softmax_kernel(
        const float* __restrict__ conf, float* __restrict__ sc,
        int* __restrict__ pcnt, int B, int N, int C) {
    int r = blockIdx.x * blockDim.x + threadIdx.x;
    if (r < B) pcnt[r] = 0;
    if (r >= B * N) return;
    const float* p = conf + (size_t)r * 81;
    float v[81];
    #pragma unroll
    for (int i = 0; i < 20; i++) {
        float4u f = *(const float4u*)(p + 4 * i);
        v[4 * i] = f.x; v[4 * i + 1] = f.y; v[4 * i + 2] = f.z; v[4 * i + 3] = f.w;
    }
    v[80] = p[80];
    float m = v[0];
    #pragma unroll
    for (int c = 1; c < 81; c++) m = fmaxf(m, v[c]);
    float s = 0.f;
    #pragma unroll
    for (int c = 0; c < 81; c++) { float e = expf(v[c] - m); v[c] = e; s += e; }
    int b = r / N, n = r % N;
    float* obase = sc + ((size_t)b * (C - 1)) * N + n;
    #pragma unroll
    for (int c = 1; c < 81; c++) obase[(size_t)(c - 1) * N] = v[c] / s;
}

// ---------------- generic-N path: per-row top-200 (reads sc) ------------------------
__global__ __launch_bounds__(TK_BS) void sel_kernel(
        const float* __restrict__ sc,
        float* __restrict__ tval, int* __restrict__ tidx,
        int B, int N, int Cm1) {
    __shared__ __align__(16) uint32_t hist[2048];
    __shared__ __align__(16) uint32_t tk[TCAP];
    __shared__ int      tix[TCAP];
    __shared__ uint32_t wsum[4];
    __shared__ uint32_t s_prefix, s_want, s_bin_a, s_bin_b;
    __shared__ uint32_t ngt, ntie, tcnt;
    __shared__ float    e_val[256];
    __shared__ int      e_idx[256];
    __shared__ int      tiebuf[256];

    int row = blockIdx.x;
    int tid = threadIdx.x;
    const float* v = sc + (size_t)row * N;
    const float4* v4 = (const float4*)v;
    int n4 = N >> 2;

    bool sampled = (N >= 2048) && ((N & 3) == 0);
    float loF = 0.f, hiF = 0.f;
    if (sampled) {
        int stride = N >> 2;
        float smp[4];
        #pragma unroll
        for (int s = 0; s < 4; s++) smp[s] = v[s * stride + tid];
        for (int i = tid; i < 2048; i += TK_BS) hist[i] = 0;
        __syncthreads();
        #pragma unroll
        for (int s = 0; s < 4; s++) {
            float f = smp[s];
            atomicAdd(&hist[fkey(f > CONF_T ? f : -1.0f) >> 21], 1u);
        }
        __syncthreads();
        suffix_select2(hist, wsum, 2048, 3u, 25u, &s_bin_a, &s_bin_b);
        uint32_t h = s_bin_a, l = s_bin_b;
        uint32_t hi_key = ((h + 1) << 21) - 1u;
        uint32_t lo_key = (l << 21) - 1u;
        hiF = fkey_inv(hi_key);
        loF = fmaxf(fkey_inv(lo_key), CONF_T);
        sampled = (l > BIN_N1);
    }

    if (tid < 256) { e_val[tid] = -1.0f; e_idx[tid] = tid; }
    if (tid == 0) { ngt = 0; ntie = 0; tcnt = 0; }
    __syncthreads();

    bool ok = false;
    uint32_t G = 0, T = 0;
    if (sampled) {
        for (int i0 = tid; i0 < n4; i0 += 16 * TK_BS) {
            float4 f[16];
            #pragma unroll
            for (int u = 0; u < 16; u++) {
                int i = i0 + u * TK_BS;
                if (i < n4) f[u] = v4[i];
            }
            #pragma unroll
            for (int u = 0; u < 16; u++) {
                int i = i0 + u * TK_BS;
                if (i < n4) {
                    float e[4] = { f[u].x, f[u].y, f[u].z, f[u].w };
                    #pragma unroll
                    for (int j = 0; j < 4; j++) {
                        float fv = e[j];
                        if (fv > loF) {
                            int idx = 4 * i + j;
                            if (fv > hiF) {
                                uint32_t p = atomicAdd(&ngt, 1u);
                                if (p < 256) { e_val[p] = fv; e_idx[p] = idx; }
                            } else {
                                uint32_t p = atomicAdd(&tcnt, 1u);
                                if (p < TCAP) { tk[p] = fkey(fv); tix[p] = idx; }
                            }
                        }
                    }
                }
            }
        }
        for (int i = (n4 << 2) + tid; i < N; i += TK_BS) {
            float fv = v[i];
            if (fv > loF) {
                if (fv > hiF) {
                    uint32_t p = atomicAdd(&ngt, 1u);
                    if (p < 256) { e_val[p] = fv; e_idx[p] = i; }
                } else {
                    uint32_t p = atomicAdd(&tcnt, 1u);
                    if (p < TCAP) { tk[p] = fkey(fv); tix[p] = i; }
                }
            }
        }
        __syncthreads();
        G = ngt; T = tcnt;
        ok = (G <= (uint32_t)M_TOP) && (T <= (uint32_t)TCAP) &&
             (G + T >= (uint32_t)M_TOP);
    }

    uint32_t kth = KEYN1, rfin = 0;
    if (ok) {
        uint32_t want_t = (uint32_t)M_TOP - G;
        if (want_t > 0) {
            for (int i = tid; i < 2048; i += TK_BS) hist[i] = 0;
            __syncthreads();
            for (int i = tid; i < (int)T; i += TK_BS) atomicAdd(&hist[tk[i] >> 21], 1u);
            __syncthreads();
            suffix_select(hist, wsum, 2048, 0u, 21, want_t, &s_prefix, &s_want);
            uint32_t pre0 = s_prefix, w0 = s_want;
            uint32_t bb0 = pre0 >> 21;
            for (int i = tid; i < 2048; i += TK_BS) hist[i] = 0;
            __syncthreads();
            for (int i = tid; i < (int)T; i += TK_BS)
                if ((tk[i] >> 21) == bb0) atomicAdd(&hist[(tk[i] >> 10) & 2047u], 1u);
            __syncthreads();
            suffix_select(hist, wsum, 2048, pre0, 10, w0, &s_prefix, &s_want);
            uint32_t pre1 = s_prefix, w1 = s_want;
            for (int i = tid; i < 1024; i += TK_BS) hist[i] = 0;
            __syncthreads();
            for (int i = tid; i < (int)T; i += TK_BS)
                if ((tk[i] >> 10) == (pre1 >> 10)) atomicAdd(&hist[tk[i] & 1023u], 1u);
            __syncthreads();
            suffix_select(hist, wsum, 1024, pre1, 0, w1, &s_prefix, &s_want);
            kth = s_prefix; rfin = s_want;
            for (int i = tid; i < (int)T; i += TK_BS) {
                uint32_t k = tk[i];
                if (k > kth) {
                    uint32_t p = atomicAdd(&ngt, 1u);
                    if (p < 256) { e_val[p] = fkey_inv(k); e_idx[p] = tix[i]; }
                } else if (k == kth) {
                    uint32_t p = atomicAdd(&ntie, 1u);
                    if (p < 256) tiebuf[p] = tix[i];
                }
            }
            __syncthreads();
        }
    } else {
        if (tid < 256) { e_val[tid] = -1.0f; e_idx[tid] = tid; }
        if (tid == 0) { ngt = 0; ntie = 0; tcnt = 0; }
        for (int i = tid; i < 2048; i += TK_BS) hist[i] = 0;
        __syncthreads();
        for (int i = tid; i < n4; i += TK_BS) {
            float4 f = v4[i];
            atomicAdd(&hist[fkey(f.x > CONF_T ? f.x : -1.0f) >> 21], 1u);
            atomicAdd(&hist[fkey(f.y > CONF_T ? f.y : -1.0f) >> 21], 1u);
            atomicAdd(&hist[fkey(f.z > CONF_T ? f.z : -1.0f) >> 21], 1u);
            atomicAdd(&hist[fkey(f.w > CONF_T ? f.w : -1.0f) >> 21], 1u);
        }
        for (int i = (n4 << 2) + tid; i < N; i += TK_BS)
            atomicAdd(&hist[fkey(v[i] > CONF_T ? v[i] : -1.0f) >> 21], 1u);
        __syncthreads();
        suffix_select(hist, wsum, 2048, 0u, 21, M_TOP, &s_prefix, &s_want);
        uint32_t b0 = s_prefix >> 21;
        uint32_t want1 = s_want;
        bool collect_ties = (b0 != BIN_N1);
        for (int i = tid; i < N; i += TK_BS) {
            float f = v[i];
            float mv = f > CONF_T ? f : -1.0f;
            uint32_t k = fkey(mv);
            uint32_t bin = k >> 21;
            if (bin > b0) {
                uint32_t p = atomicAdd(&ngt, 1u);
                if (p < 256) { e_val[p] = mv; e_idx[p] = i; }
            } else if (bin == b0 && collect_ties) {
                uint32_t p = atomicAdd(&tcnt, 1u);
                if (p < TCAP) { tk[p] = k; tix[p] = i; }
            }
        }
        __syncthreads();
        if (collect_ties && tcnt <= TCAP) {
            int Tl = (int)tcnt;
            for (int i = tid; i < 2048; i += TK_BS) hist[i] = 0;
            __syncthreads();
            for (int i = tid; i < Tl; i += TK_BS) atomicAdd(&hist[(tk[i] >> 10) & 2047u], 1u);
            __syncthreads();
            suffix_select(hist, wsum, 2048, b0 << 21, 10, want1, &s_prefix, &s_want);
            uint32_t pre2 = s_prefix; uint32_t want2 = s_want;
            uint32_t b1 = (pre2 >> 10) & 2047u;
            for (int i = tid; i < 1024; i += TK_BS) hist[i] = 0;
            __syncthreads();
            for (int i = tid; i < Tl; i += TK_BS)
                if (((tk[i] >> 10) & 2047u) == b1) atomicAdd(&hist[tk[i] & 1023u], 1u);
            __syncthreads();
            suffix_select(hist, wsum, 1024, pre2, 0, want2, &s_prefix, &s_want);
            kth = s_prefix; rfin = s_want;
            for (int i = tid; i < Tl; i += TK_BS) {
                uint32_t k = tk[i];
                if (k > kth) {
                    uint32_t p = atomicAdd(&ngt, 1u);
                    if (p < 256) { e_val[p] = fkey_inv(k); e_idx[p] = tix[i]; }
                } else if (k == kth) {
                    uint32_t p = atomicAdd(&ntie, 1u);
                    if (p < 256) tiebuf[p] = tix[i];
                }
            }
            __syncthreads();
        } else if (collect_ties) {
            const int shifts[2] = {10, 0};
            const int nbins_[2] = {2048, 1024};
            if (tid == 0) { s_prefix = b0 << 21; s_want = want1; }
            __syncthreads();
            for (int lev = 0; lev < 2; lev++) {
                int shift = shifts[lev];
                int nb = nbins_[lev];
                uint32_t bmask = (uint32_t)nb - 1u;
                uint32_t pref = s_prefix, wantv = s_want;
                uint32_t pmask = 0xFFFFFFFFu << (shift + ((nb == 2048) ? 11 : 10));
                for (int i = tid; i < nb; i += TK_BS) hist[i] = 0;
                __syncthreads();
                for (int i = tid; i < N; i += TK_BS) {
                    float f = v[i];
                    uint32_t k = fkey(f > CONF_T ? f : -1.0f);
                    if ((k & pmask) == (pref & pmask)) atomicAdd(&hist[(k >> shift) & bmask], 1u);
                }
                __syncthreads();
                suffix_select(hist, wsum, nb, pref, shift, wantv, &s_prefix, &s_want);
            }
            kth = s_prefix; rfin = s_want;
            for (int i = tid; i < N; i += TK_BS) {
                float f = v[i];
                float mv = f > CONF_T ? f : -1.0f;
                uint32_t k = fkey(mv);
                if ((k >> 21) == b0) {
                    if (k > kth) {
                        uint32_t p = atomicAdd(&ngt, 1u);
                        if (p < 256) { e_val[p] = mv; e_idx[p] = i; }
                    } else if (k == kth) {
                        uint32_t p = atomicAdd(&ntie, 1u);
                        if (p < 256) tiebuf[p] = i;
                    }
                }
            }
            __syncthreads();
        }
    }

    uint32_t gcount = min(ngt, (uint32_t)M_TOP);
    uint32_t nt = min(ntie, 256u);
    if (tid < (int)nt) {
        int mine = tiebuf[tid];
        uint32_t rk = 0;
        for (uint32_t j = 0; j < nt; j++) if (tiebuf[j] < mine) rk++;
        if (rk < rfin) {
            uint32_t slot = gcount + rk;
            if (slot < M_TOP) { e_val[slot] = fkey_inv(kth); e_idx[slot] = mine; }
        }
    }
    __syncthreads();
    uint64_t* e_pack = (uint64_t*)tk;
    if (tid < 256)
        e_pack[tid] = ((uint64_t)fkey(e_val[tid]) << 32) | (uint32_t)~(uint32_t)e_idx[tid];
    __syncthreads();
    if (tid < M_TOP) {
        uint64_t mine = e_pack[tid];
        uint32_t rk = 0;
        for (int j = 0; j < M_TOP; j++) rk += (e_pack[j] > mine) ? 1u : 0u;
        tval[(size_t)row * M_TOP + rk] = e_val[tid];
        tidx[(size_t)row * M_TOP + rk] = e_idx[tid];
    }
}

// ---------------- decode + bitmask NMS (upper triangle) + compaction ----------------
__global__ __launch_bounds__(NMS_BS) void nms_kernel(
        const float* __restrict__ tval, const int* __restrict__ tidx,
        const float* __restrict__ loc, const float* __restrict__ dbox,
        float* __restrict__ cand,
        float* __restrict__ cmpval, int* __restrict__ cmpidx,
        int* __restrict__ pcnt,
        int B, int N, int Cm1, int M) {
    __shared__ __align__(16) float4 s_bb[M_TOP];
    __shared__ float    s_ar[M_TOP];
    __shared__ float    s_sc[M_TOP];
    __shared__ __align__(16) uint64_t supT[M_TOP * 4];

    int row = blockIdx.x;
    int b = row / Cm1, c = row % Cm1;
    int tid = threadIdx.x;

    if (tid < M_TOP) {
        float mv = tval[(size_t)row * M_TOP + tid];
        int   mi = tidx[(size_t)row * M_TOP + tid];
        float4 l = ((const float4*)loc)[(size_t)b * N + mi];
        float4 d = ((const float4*)dbox)[mi];
        float4 bx = decode_box(l, d);
        ((float4*)cand)[(size_t)row * M_TOP + tid] = bx;
        s_sc[tid] = mv;
        s_bb[tid] = bx;
        s_ar[tid] = (bx.z - bx.x) * (bx.w - bx.y);
    }
    __syncthreads();

    // upper triangle only: a kept box i only affects lower-ranked (j > i) boxes;
    // clearing bits for j <= i is a no-op on recorded keep flags.
    for (int t = tid; t < M_TOP * 4; t += NMS_BS) {
        int iw = t / M_TOP;
        int j  = t - iw * M_TOP;
        int i0 = iw << 6;
        uint64_t mm = 0;
        int iN = j - i0; if (iN > 64) iN = 64;
        if (iN > 0) {
            float4 bj = s_bb[j];
            float arJ = s_ar[j];
            for (int k = 0; k < iN; k++) {
                float4 bi = s_bb[i0 + k];          // broadcast across lanes
                float xx1 = fmaxf(bi.x, bj.x);
                float yy1 = fmaxf(bi.y, bj.y);
                float xx2 = fminf(bi.z, bj.z);
                float yy2 = fminf(bi.w, bj.w);
                float inter = fmaxf(xx2 - xx1, 0.f) * fmaxf(yy2 - yy1, 0.f);
                float uni = (arJ - inter) + s_ar[i0 + k];
                float iou = inter / uni;           // exact div: bit-identical
                if (!(iou <= NMS_T)) mm |= (1ull << k);   // NaN suppresses
            }
        }
        supT[(j << 2) + iw] = mm;
    }
    __syncthreads();

    if (tid < 64) {
        int lane = tid;
        uint64_t st0[4], st1[4], st2[4], st3[4];
        bool alive[4]; int keepb[4];
        #pragma unroll
        for (int s = 0; s < 4; s++) {
            int j = (s << 6) + lane;
            bool inb = (j < M_TOP);
            uint64_t w0 = inb ? supT[(j << 2) + 0] : 0ull;
            uint64_t w1 = inb ? supT[(j << 2) + 1] : 0ull;
            uint64_t w2 = inb ? supT[(j << 2) + 2] : 0ull;
            uint64_t w3 = inb ? supT[(j << 2) + 3] : 0ull;
            if (s == 0) { st0[0]=w0; st0[1]=w1; st0[2]=w2; st0[3]=w3; }
            if (s == 1) { st1[0]=w0; st1[1]=w1; st1[2]=w2; st1[3]=w3; }
            if (s == 2) { st2[0]=w0; st2[1]=w1; st2[2]=w2; st2[3]=w3; }
            if (s == 3) { st3[0]=w0; st3[1]=w1; st3[2]=w2; st3[3]=w3; }
            alive[s] = inb ? (s_sc[j] > CONF_T) : false;
            keepb[s] = 0;
        }
        #pragma unroll
        for (int iw = 0; iw < 4; iw++) {
            int lim = M_TOP - (iw << 6); if (lim > 64) lim = 64; if (lim < 0) lim = 0;
            for (int b2 = 0; b2 < lim; b2++) {
                uint64_t mask = __ballot(alive[iw]);
                if ((mask >> b2) & 1ull) {
                    if (lane == b2) keepb[iw] = 1;
                    alive[0] = alive[0] && !((st0[iw] >> b2) & 1ull);
                    alive[1] = alive[1] && !((st1[iw] >> b2) & 1ull);
                    alive[2] = alive[2] && !((st2[iw] >> b2) & 1ull);
                    alive[3] = alive[3] && !((st3[iw] >> b2) & 1ull);
                }
            }
        }
        unsigned long long ball[4];
        int total = 0;
        #pragma unroll
        for (int s = 0; s < 4; s++) { ball[s] = __ballot(keepb[s] != 0); total += (int)__popcll(ball[s]); }
        int base = 0;
        if (lane == 0 && total > 0) base = atomicAdd(&pcnt[b], total);
        base = __shfl(base, 0);
        unsigned long long lower = (lane == 0) ? 0ull : (~0ull >> (64 - lane));
        int off = base;
        #pragma unroll
        for (int s = 0; s < 4; s++) {
            if (keepb[s]) {
                int pos = off + (int)__popcll(ball[s] & lower);
                cmpval[(size_t)b * M + pos] = s_sc[(s << 6) + lane];
                cmpidx[(size_t)b * M + pos] = c * M_TOP + (s << 6) + lane;
            }
            off += (int)__popcll(ball[s]);
        }
    }
}

// ---------------- top-200 of positives -> compact (val,idx) list --------------------
#define GT_BS 1024
__global__ __launch_bounds__(GT_BS) void gtop_kernel(
        const float* __restrict__ cmpval, const int* __restrict__ cmpidx,
        const int* __restrict__ pcnt, float* __restrict__ gl_val,
        int* __restrict__ gl_idx, int* __restrict__ gl_cnt, int M) {
    int b = blockIdx.x;
    int tid = threadIdx.x;
    int P = pcnt[b];
    const float* cv = cmpval + (size_t)b * M;
    const int*   ci = cmpidx + (size_t)b * M;
    if (P <= M_TOP) {
        for (int i = tid; i < P; i += GT_BS) {
            gl_val[b * M_TOP + i] = cv[i];
            gl_idx[b * M_TOP + i] = ci[i];
        }
        if (tid == 0) gl_cnt[b] = P;
        return;
    }
    __shared__ uint32_t hist[256];
    __shared__ uint32_t wsum[4];
    __shared__ uint32_t s_prefix, s_want;
    __shared__ int tiebuf[256];
    __shared__ uint32_t ntie, wcnt;
    __shared__ int cutoff;
    if (tid == 0) { s_prefix = 0; s_want = M_TOP; }
    for (int pass = 0; pass < 4; pass++) {
        if (tid < 256) hist[tid] = 0;
        __syncthreads();
        uint32_t prefix = s_prefix;
        int shift = 24 - 8 * pass;
        for (int i = tid; i < P; i += GT_BS) {
            uint32_t k = fkey(cv[i]);
            bool okm = (pass == 0) || ((k >> (shift + 8)) == (prefix >> (shift + 8)));
            if (okm) atomicAdd(&hist[(k >> shift) & 255u], 1u);
        }
        __syncthreads();
        uint32_t wantv = s_want;
        suffix_select(hist, wsum, 256, prefix, shift, wantv, &s_prefix, &s_want);
    }
    uint32_t kth = s_prefix, rfin = s_want;
    if (tid == 0) { ntie = 0; cutoff = -1; wcnt = 0; }
    __syncthreads();
    for (int i = tid; i < P; i += GT_BS) {
        if (fkey(cv[i]) == kth) { uint32_t p = atomicAdd(&ntie, 1u); if (p < 256) tiebuf[p] = ci[i]; }
    }
    __syncthreads();
    uint32_t nt = min(ntie, 256u);
    if (tid < (int)nt) {
        int mine = tiebuf[tid];
        uint32_t rk = 0;
        for (uint32_t j = 0; j < nt; j++) if (tiebuf[j] < mine) rk++;
        if (rk == rfin - 1) cutoff = mine;
    }
    __syncthreads();
    int cut = cutoff;
    for (int i = tid; i < P; i += GT_BS) {
        uint32_t k = fkey(cv[i]);
        if (k > kth || (k == kth && ci[i] <= cut)) {
            uint32_t p = atomicAdd(&wcnt, 1u);
            gl_val[b * M_TOP + p] = cv[i];
            gl_idx[b * M_TOP + p] = ci[i];
        }
    }
    if (tid == 0) gl_cnt[b] = M_TOP;
}

// ---------------- per-class sort + FULL output write (no memset) --------------------
__global__ __launch_bounds__(256) void out_kernel(
        const float* __restrict__ gl_val, const int* __restrict__ gl_idx,
        const int* __restrict__ gl_cnt, const float* __restrict__ cand,
        float* __restrict__ out, int C, int Cm1) {
    int row = blockIdx.x;
    int b = row / C, cc = row % C;
    int tid = threadIdx.x;
    size_t oslab = (size_t)row * M_TOP * 5;
    if (cc == 0) {
        float4 z; z.x = 0.f; z.y = 0.f; z.z = 0.f; z.w = 0.f;
        float4* o4 = (float4*)(out + oslab);
        for (int i = tid; i < M_TOP * 5 / 4; i += 256) o4[i] = z;
        return;
    }
    int c = cc - 1;
    __shared__ float lv[M_TOP];
    __shared__ int   lm[M_TOP];
    __shared__ uint32_t nloc;
    if (tid == 0) nloc = 0;
    __syncthreads();
    int cnt = gl_cnt[b];
    for (int i = tid; i < cnt; i += 256) {
        int idx = gl_idx[b * M_TOP + i];
        if (idx / M_TOP == c) {
            uint32_t p = atomicAdd(&nloc, 1u);
            lv[p] = gl_val[b * M_TOP + i];
            lm[p] = idx % M_TOP;
        }
    }
    __syncthreads();
    int nc = (int)nloc;
    if (tid < M_TOP) {
        if (tid < nc) {
            float v = lv[tid]; int m = lm[tid];
            int rk = 0;
            for (int j = 0; j < nc; j++)
                if (lv[j] > v || (lv[j] == v && lm[j] < m)) rk++;
            float4 bb = ((const float4*)cand)[((size_t)(b * Cm1 + c)) * M_TOP + m];
            size_t o = oslab + (size_t)rk * 5;
            out[o] = v; out[o + 1] = bb.x; out[o + 2] = bb.y;
            out[o + 3] = bb.z; out[o + 4] = bb.w;
        } else {
            size_t o = oslab + (size_t)tid * 5;
            out[o] = 0.f; out[o + 1] = 0.f; out[o + 2] = 0.f;
            out[o + 3] = 0.f; out[o + 4] = 0.f;
        }
    }
}

extern "C" void kernel_launch(void* const* d_in, const int* in_sizes, int n_in,
                              void* d_out, int out_size, void* d_ws, size_t ws_size,
                              hipStream_t stream) {
    const float* loc  = (const float*)d_in[0];
    const float* conf = (const float*)d_in[1];
    const float* dbox = (const float*)d_in[2];
    int N   = in_sizes[2] / 4;
    int B   = in_sizes[0] / (4 * N);
    int C   = in_sizes[1] / (B * N);
    int Cm1 = C - 1;
    int M   = Cm1 * M_TOP;
    int R   = B * Cm1;

    char* ws = (char*)d_ws;
    size_t off = 0;
    auto alloc = [&](size_t bytes) -> char* {
        char* p = ws + off;
        off = (off + bytes + 255) & ~(size_t)255;
        return p;
    };
    float* cand   = (float*)alloc((size_t)B * M * 4 * sizeof(float));
    int*   pcnt   = (int*)alloc((size_t)B * sizeof(int));
    float* cmpval = (float*)alloc((size_t)B * M * sizeof(float));
    int*   cmpidx = (int*)alloc((size_t)B * M * sizeof(int));
    float* gl_val = (float*)alloc((size_t)B * M_TOP * sizeof(float));
    int*   gl_idx = (int*)alloc((size_t)B * M_TOP * sizeof(int));
    int*   gl_cnt = (int*)alloc((size_t)B * sizeof(int));
    float* tval   = (float*)alloc((size_t)R * M_TOP * sizeof(float));
    int*   tidx   = (int*)alloc((size_t)R * M_TOP * sizeof(int));

    bool fast = (N >= 2048) && ((N & 255) == 0);
    if (fast) {
        float*    samp  = (float*)alloc((size_t)R * 2048 * sizeof(float));
        float*    thrLo = (float*)alloc((size_t)R * sizeof(float));
        float*    thrHi = (float*)alloc((size_t)R * sizeof(float));
        uint32_t* gcnt  = (uint32_t*)alloc((size_t)R * sizeof(uint32_t));
        uint32_t* tcnt  = (uint32_t*)alloc((size_t)R * sizeof(uint32_t));
        float*    gvalb = (float*)alloc((size_t)R * GCAP * sizeof(float));
        int*      gidxb = (int*)alloc((size_t)R * GCAP * sizeof(int));
        uint32_t* tkeyb = (uint32_t*)alloc((size_t)R * TCAP * sizeof(uint32_t));
        int*      tixgb = (int*)alloc((size_t)R * TCAP * sizeof(int));

        samp_kernel<<<B * 8, 256, 0, stream>>>(conf, samp, N, Cm1);
        thr_kernel<<<R, TK_BS, 0, stream>>>(samp, thrLo, thrHi, gcnt, tcnt, pcnt, Cm1);
        fsel_kernel<<<B * (N >> 6), FS_BS, 0, stream>>>(conf, thrLo, thrHi,
                                                        gvalb, gidxb, gcnt,
                                                        tkeyb, tixgb, tcnt, N, Cm1);
        fin_kernel<<<R, FIN_BS, 0, stream>>>(conf, thrLo, gvalb, gidxb, gcnt,
                                             tkeyb, tixgb, tcnt, tval, tidx, N, Cm1);
    } else {
        float* sc = (float*)alloc((size_t)B * Cm1 * N * sizeof(float));
        int bn = B * N;
        softmax_kernel<<<(bn + 255) / 256, 256, 0, stream>>>(conf, sc, pcnt, B, N, C);
        sel_kernel<<<R, TK_BS, 0, stream>>>(sc, tval, tidx, B, N, Cm1);
    }
    nms_kernel<<<R, NMS_BS, 0, stream>>>(tval, tidx, loc, dbox, cand,
                                         cmpval, cmpidx, pcnt, B, N, Cm1, M);
    gtop_kernel<<<B, GT_BS, 0, stream>>>(cmpval, cmpidx, pcnt, gl_val, gl_idx, gl_cnt, M);
    out_kernel<<<B * C, 256, 0, stream>>>(gl_val, gl_idx, gl_cnt, cand, (float*)d_out, C, Cm1);
}

// Round 19
// 268.442 us; speedup vs baseline: 2.4131x; 2.4131x over previous
//
#include <hip/hip_runtime.h>
#include <stdint.h>

#define CONF_T 0.01f
#define NMS_T  0.45f
#define M_TOP  200
#define TK_BS  512    // topk block size (8 waves)
#define TCAP   2048   // topk bracket buffer capacity (LDS); overflow -> exact fallback

typedef float float4u __attribute__((ext_vector_type(4), aligned(4)));

__device__ __forceinline__ uint32_t fkey(float f) {
    uint32_t u = __float_as_uint(f);
    return (u & 0x80000000u) ? ~u : (u | 0x80000000u);
}
__device__ __forceinline__ float fkey_inv(uint32_t k) {
    uint32_t u = (k & 0x80000000u) ? (k & 0x7FFFFFFFu) : ~k;
    return __uint_as_float(u);
}

// Parallel suffix-scan bin selection over nb bins (nb multiple of 256).
// Scan work is done by threads 0..255; all TK_BS threads must reach barriers.
__device__ __forceinline__ void suffix_select(
        uint32_t* hist, uint32_t* wsum, int nb, uint32_t pref, int shift,
        uint32_t wantv, uint32_t* s_prefix, uint32_t* s_want) {
    int tid = threadIdx.x;
    int lane = tid & 63, w = tid >> 6;
    int bpt = nb >> 8;
    int base = tid * bpt;
    uint32_t loc = 0, sfx = 0;
    if (tid < 256) {
        for (int j = 0; j < bpt; j++) loc += hist[base + j];
        sfx = loc;
        #pragma unroll
        for (int d = 1; d < 64; d <<= 1) {
            uint32_t y = __shfl_down(sfx, d);
            if (lane + d < 64) sfx += y;
        }
        if (lane == 0) wsum[w] = sfx;
    }
    __syncthreads();
    if (tid < 256) {
        uint32_t later = 0;
        for (int j = w + 1; j < 4; j++) later += wsum[j];
        uint32_t run = (sfx - loc) + later;
        for (int j = bpt - 1; j >= 0; j--) {
            uint32_t h = hist[base + j];
            uint32_t s2 = run + h;
            if (run < wantv && s2 >= wantv) {
                *s_prefix = pref | ((uint32_t)(base + j) << shift);
                *s_want   = wantv - run;
            }
            run = s2;
        }
    }
    __syncthreads();
}

// Dual-rank variant: boundary bins for TWO wants in one scan.
__device__ __forceinline__ void suffix_select2(
        uint32_t* hist, uint32_t* wsum, int nb, uint32_t want_a, uint32_t want_b,
        uint32_t* s_bin_a, uint32_t* s_bin_b) {
    int tid = threadIdx.x;
    int lane = tid & 63, w = tid >> 6;
    int bpt = nb >> 8;
    int base = tid * bpt;
    uint32_t loc = 0, sfx = 0;
    if (tid < 256) {
        for (int j = 0; j < bpt; j++) loc += hist[base + j];
        sfx = loc;
        #pragma unroll
        for (int d = 1; d < 64; d <<= 1) {
            uint32_t y = __shfl_down(sfx, d);
            if (lane + d < 64) sfx += y;
        }
        if (lane == 0) wsum[w] = sfx;
    }
    __syncthreads();
    if (tid < 256) {
        uint32_t later = 0;
        for (int j = w + 1; j < 4; j++) later += wsum[j];
        uint32_t run = (sfx - loc) + later;
        for (int j = bpt - 1; j >= 0; j--) {
            uint32_t h = hist[base + j];
            uint32_t s2 = run + h;
            if (run < want_a && s2 >= want_a) *s_bin_a = (uint32_t)(base + j);
            if (run < want_b && s2 >= want_b) *s_bin_b = (uint32_t)(base + j);
            run = s2;
        }
    }
    __syncthreads();
}

__device__ __forceinline__ float4 decode_box(float4 l, float4 d) {
    float cx = d.x + (l.x * 0.1f) * d.z;
    float cy = d.y + (l.y * 0.1f) * d.w;
    float w  = d.z * expf(l.z * 0.2f);
    float h  = d.w * expf(l.w * 0.2f);
    float x1 = cx - w * 0.5f, y1 = cy - h * 0.5f;
    float x2 = x1 + w, y2 = y1 + h;
    float4 o;
    o.x = fminf(fmaxf(x1, 0.f), 1.f);
    o.y = fminf(fmaxf(y1, 0.f), 1.f);
    o.z = fminf(fmaxf(x2, 0.f), 1.f);
    o.w = fminf(fmaxf(y2, 0.f), 1.f);
    return o;
}

// ---------------- Kernel B: softmax + transpose (register-resident) + pcnt init ------
__global__ __launch_bounds__(256, 4) void softmax_kernel(
        const float* __restrict__ conf, float* __restrict__ sc,
        int* __restrict__ pcnt, int B, int N, int C) {
    int r = blockIdx.x * blockDim.x + threadIdx.x;
    if (r < B) pcnt[r] = 0;                 // zero pcnt for the topk dispatch
    if (r >= B * N) return;
    const float* p = conf + (size_t)r * 81;
    float v[81];
    #pragma unroll
    for (int i = 0; i < 20; i++) {
        float4u f = *(const float4u*)(p + 4 * i);
        v[4 * i] = f.x; v[4 * i + 1] = f.y; v[4 * i + 2] = f.z; v[4 * i + 3] = f.w;
    }
    v[80] = p[80];
    float m = v[0];
    #pragma unroll
    for (int c = 1; c < 81; c++) m = fmaxf(m, v[c]);
    float s = 0.f;
    #pragma unroll
    for (int c = 0; c < 81; c++) { float e = expf(v[c] - m); v[c] = e; s += e; }
    int b = r / N, n = r % N;
    float* obase = sc + ((size_t)b * (C - 1)) * N + n;
    #pragma unroll
    for (int c = 1; c < 81; c++) obase[(size_t)(c - 1) * N] = v[c] / s;
}

// ---------------- Kernel C: top-200 + inline decode + bitmask NMS -------------------
__global__ __launch_bounds__(TK_BS) void topk_kernel(
        const float* __restrict__ sc, const float* __restrict__ loc,
        const float* __restrict__ dbox,
        float* __restrict__ cand,
        float* __restrict__ cmpval, int* __restrict__ cmpidx,
        int* __restrict__ pcnt,
        int B, int N, int Cm1, int M) {
    const uint32_t KEYN1 = 0x407FFFFFu;        // fkey(-1.0f)
    const uint32_t BIN_N1 = KEYN1 >> 21;       // 0x203
    __shared__ __align__(16) uint32_t hist[2048];   // reused as sup-matrix (200x4 u64)
    __shared__ __align__(16) uint32_t tk[TCAP];     // reused as e_pack (256 u64)
    __shared__ int      tix[TCAP];
    __shared__ uint32_t wsum[4];
    __shared__ uint32_t s_prefix, s_want, s_bin_a, s_bin_b;
    __shared__ uint32_t ngt, ntie, tcnt;
    __shared__ float    e_val[256];
    __shared__ int      e_idx[256];
    __shared__ int      tiebuf[256];
    __shared__ float    s_sc[M_TOP];
    __shared__ __align__(16) float4 s_bb[M_TOP];
    __shared__ float    s_ar[M_TOP];

    int row = blockIdx.x;                      // b*Cm1 + c
    int b = row / Cm1, c = row % Cm1;
    int tid = threadIdx.x;
    const float* v = sc + (size_t)row * N;
    const float4* v4 = (const float4*)v;
    int n4 = N >> 2;

    // ---- sample phase: 2048 strided samples, register->histogram (no LDS staging) ---
    bool sampled = (N >= 2048) && ((N & 3) == 0);
    float loF = 0.f, hiF = 0.f;
    if (sampled) {
        int stride = N >> 2;
        float smp[4];
        #pragma unroll
        for (int s = 0; s < 4; s++) smp[s] = v[s * stride + tid];
        for (int i = tid; i < 2048; i += TK_BS) hist[i] = 0;
        __syncthreads();
        #pragma unroll
        for (int s = 0; s < 4; s++) {
            float f = smp[s];
            atomicAdd(&hist[fkey(f > CONF_T ? f : -1.0f) >> 21], 1u);
        }
        __syncthreads();
        suffix_select2(hist, wsum, 2048, 3u, 25u, &s_bin_a, &s_bin_b);
        uint32_t h = s_bin_a, l = s_bin_b;
        uint32_t hi_key = ((h + 1) << 21) - 1u;    // h=2047 wraps to 0xFFFFFFFF (G=0)
        uint32_t lo_key = (l << 21) - 1u;
        // float-domain thresholds: k > key  <=>  f > fkey_inv(key)  (monotonic).
        // loF folds the CONF_T mask: mv > lo  <=>  f > max(lo, CONF_T) (lo > -1 here).
        hiF = fkey_inv(hi_key);
        loF = fmaxf(fkey_inv(lo_key), CONF_T);
        sampled = (l > BIN_N1);
    }

    if (tid < 256) { e_val[tid] = -1.0f; e_idx[tid] = tid; }
    if (tid == 0) { ngt = 0; ntie = 0; tcnt = 0; }
    __syncthreads();

    bool ok = false;
    uint32_t G = 0, T = 0;
    if (sampled) {
        // ---- the one full sweep: single float compare per element; fkey only for
        //      the ~400 survivors per row ----
        for (int i0 = tid; i0 < n4; i0 += 8 * TK_BS) {
            float4 f[8];
            #pragma unroll
            for (int u = 0; u < 8; u++) {
                int i = i0 + u * TK_BS;
                if (i < n4) f[u] = v4[i];
            }
            #pragma unroll
            for (int u = 0; u < 8; u++) {
                int i = i0 + u * TK_BS;
                if (i < n4) {
                    float e[4] = { f[u].x, f[u].y, f[u].z, f[u].w };
                    #pragma unroll
                    for (int j = 0; j < 4; j++) {
                        float fv = e[j];
                        if (fv > loF) {                 // implies fv > CONF_T
                            int idx = 4 * i + j;
                            if (fv > hiF) {
                                uint32_t p = atomicAdd(&ngt, 1u);
                                if (p < 256) { e_val[p] = fv; e_idx[p] = idx; }
                            } else {
                                uint32_t p = atomicAdd(&tcnt, 1u);
                                if (p < TCAP) { tk[p] = fkey(fv); tix[p] = idx; }
                            }
                        }
                    }
                }
            }
        }
        for (int i = (n4 << 2) + tid; i < N; i += TK_BS) {
            float fv = v[i];
            if (fv > loF) {
                if (fv > hiF) {
                    uint32_t p = atomicAdd(&ngt, 1u);
                    if (p < 256) { e_val[p] = fv; e_idx[p] = i; }
                } else {
                    uint32_t p = atomicAdd(&tcnt, 1u);
                    if (p < TCAP) { tk[p] = fkey(fv); tix[p] = i; }
                }
            }
        }
        __syncthreads();
        G = ngt; T = tcnt;
        ok = (G <= (uint32_t)M_TOP) && (T <= (uint32_t)TCAP) &&
             (G + T >= (uint32_t)M_TOP);
    }

    uint32_t kth = KEYN1, rfin = 0;
    if (ok) {
        uint32_t want_t = (uint32_t)M_TOP - G;
        if (want_t > 0) {
            for (int i = tid; i < 2048; i += TK_BS) hist[i] = 0;
            __syncthreads();
            for (int i = tid; i < (int)T; i += TK_BS) atomicAdd(&hist[tk[i] >> 21], 1u);
            __syncthreads();
            suffix_select(hist, wsum, 2048, 0u, 21, want_t, &s_prefix, &s_want);
            uint32_t pre0 = s_prefix, w0 = s_want;
            uint32_t bb0 = pre0 >> 21;
            for (int i = tid; i < 2048; i += TK_BS) hist[i] = 0;
            __syncthreads();
            for (int i = tid; i < (int)T; i += TK_BS)
                if ((tk[i] >> 21) == bb0) atomicAdd(&hist[(tk[i] >> 10) & 2047u], 1u);
            __syncthreads();
            suffix_select(hist, wsum, 2048, pre0, 10, w0, &s_prefix, &s_want);
            uint32_t pre1 = s_prefix, w1 = s_want;
            for (int i = tid; i < 1024; i += TK_BS) hist[i] = 0;
            __syncthreads();
            for (int i = tid; i < (int)T; i += TK_BS)
                if ((tk[i] >> 10) == (pre1 >> 10)) atomicAdd(&hist[tk[i] & 1023u], 1u);
            __syncthreads();
            suffix_select(hist, wsum, 1024, pre1, 0, w1, &s_prefix, &s_want);
            kth = s_prefix; rfin = s_want;
            for (int i = tid; i < (int)T; i += TK_BS) {
                uint32_t k = tk[i];
                if (k > kth) {
                    uint32_t p = atomicAdd(&ngt, 1u);
                    if (p < 256) { e_val[p] = fkey_inv(k); e_idx[p] = tix[i]; }
                } else if (k == kth) {
                    uint32_t p = atomicAdd(&ntie, 1u);
                    if (p < 256) tiebuf[p] = tix[i];
                }
            }
            __syncthreads();
        }
    } else {
        // ---- fallback: exact 2-sweep histogram path ----
        if (tid < 256) { e_val[tid] = -1.0f; e_idx[tid] = tid; }
        if (tid == 0) { ngt = 0; ntie = 0; tcnt = 0; }
        for (int i = tid; i < 2048; i += TK_BS) hist[i] = 0;
        __syncthreads();
        for (int i = tid; i < n4; i += TK_BS) {
            float4 f = v4[i];
            atomicAdd(&hist[fkey(f.x > CONF_T ? f.x : -1.0f) >> 21], 1u);
            atomicAdd(&hist[fkey(f.y > CONF_T ? f.y : -1.0f) >> 21], 1u);
            atomicAdd(&hist[fkey(f.z > CONF_T ? f.z : -1.0f) >> 21], 1u);
            atomicAdd(&hist[fkey(f.w > CONF_T ? f.w : -1.0f) >> 21], 1u);
        }
        for (int i = (n4 << 2) + tid; i < N; i += TK_BS)
            atomicAdd(&hist[fkey(v[i] > CONF_T ? v[i] : -1.0f) >> 21], 1u);
        __syncthreads();
        suffix_select(hist, wsum, 2048, 0u, 21, M_TOP, &s_prefix, &s_want);
        uint32_t b0 = s_prefix >> 21;
        uint32_t want1 = s_want;
        bool collect_ties = (b0 != BIN_N1);
        for (int i = tid; i < N; i += TK_BS) {
            float f = v[i];
            float mv = f > CONF_T ? f : -1.0f;
            uint32_t k = fkey(mv);
            uint32_t bin = k >> 21;
            if (bin > b0) {
                uint32_t p = atomicAdd(&ngt, 1u);
                if (p < 256) { e_val[p] = mv; e_idx[p] = i; }
            } else if (bin == b0 && collect_ties) {
                uint32_t p = atomicAdd(&tcnt, 1u);
                if (p < TCAP) { tk[p] = k; tix[p] = i; }
            }
        }
        __syncthreads();
        if (collect_ties && tcnt <= TCAP) {
            int Tl = (int)tcnt;
            for (int i = tid; i < 2048; i += TK_BS) hist[i] = 0;
            __syncthreads();
            for (int i = tid; i < Tl; i += TK_BS) atomicAdd(&hist[(tk[i] >> 10) & 2047u], 1u);
            __syncthreads();
            suffix_select(hist, wsum, 2048, b0 << 21, 10, want1, &s_prefix, &s_want);
            uint32_t pre2 = s_prefix; uint32_t want2 = s_want;
            uint32_t b1 = (pre2 >> 10) & 2047u;
            for (int i = tid; i < 1024; i += TK_BS) hist[i] = 0;
            __syncthreads();
            for (int i = tid; i < Tl; i += TK_BS)
                if (((tk[i] >> 10) & 2047u) == b1) atomicAdd(&hist[tk[i] & 1023u], 1u);
            __syncthreads();
            suffix_select(hist, wsum, 1024, pre2, 0, want2, &s_prefix, &s_want);
            kth = s_prefix; rfin = s_want;
            for (int i = tid; i < Tl; i += TK_BS) {
                uint32_t k = tk[i];
                if (k > kth) {
                    uint32_t p = atomicAdd(&ngt, 1u);
                    if (p < 256) { e_val[p] = fkey_inv(k); e_idx[p] = tix[i]; }
                } else if (k == kth) {
                    uint32_t p = atomicAdd(&ntie, 1u);
                    if (p < 256) tiebuf[p] = tix[i];
                }
            }
            __syncthreads();
        } else if (collect_ties) {
            const int shifts[2] = {10, 0};
            const int nbins_[2] = {2048, 1024};
            if (tid == 0) { s_prefix = b0 << 21; s_want = want1; }
            __syncthreads();
            for (int lev = 0; lev < 2; lev++) {
                int shift = shifts[lev];
                int nb = nbins_[lev];
                uint32_t bmask = (uint32_t)nb - 1u;
                uint32_t pref = s_prefix, wantv = s_want;
                uint32_t pmask = 0xFFFFFFFFu << (shift + ((nb == 2048) ? 11 : 10));
                for (int i = tid; i < nb; i += TK_BS) hist[i] = 0;
                __syncthreads();
                for (int i = tid; i < N; i += TK_BS) {
                    float f = v[i];
                    uint32_t k = fkey(f > CONF_T ? f : -1.0f);
                    if ((k & pmask) == (pref & pmask)) atomicAdd(&hist[(k >> shift) & bmask], 1u);
                }
                __syncthreads();
                suffix_select(hist, wsum, nb, pref, shift, wantv, &s_prefix, &s_want);
            }
            kth = s_prefix; rfin = s_want;
            for (int i = tid; i < N; i += TK_BS) {
                float f = v[i];
                float mv = f > CONF_T ? f : -1.0f;
                uint32_t k = fkey(mv);
                if ((k >> 21) == b0) {
                    if (k > kth) {
                        uint32_t p = atomicAdd(&ngt, 1u);
                        if (p < 256) { e_val[p] = mv; e_idx[p] = i; }
                    } else if (k == kth) {
                        uint32_t p = atomicAdd(&ntie, 1u);
                        if (p < 256) tiebuf[p] = i;
                    }
                }
            }
            __syncthreads();
        }
    }

    // ---- ties, rank order (packed u64 keys), inline box decode -> LDS + cand ----
    uint32_t gcount = min(ngt, (uint32_t)M_TOP);
    uint32_t nt = min(ntie, 256u);
    if (tid < (int)nt) {
        int mine = tiebuf[tid];
        uint32_t rk = 0;
        for (uint32_t j = 0; j < nt; j++) if (tiebuf[j] < mine) rk++;
        if (rk < rfin) {
            uint32_t slot = gcount + rk;
            if (slot < M_TOP) { e_val[slot] = fkey_inv(kth); e_idx[slot] = mine; }
        }
    }
    __syncthreads();
    // pack (key desc, idx asc) into one u64 so rank loop is 1 ds_read_b64 + 1 cmp
    uint64_t* e_pack = (uint64_t*)tk;          // tk is dead past this point
    if (tid < 256)
        e_pack[tid] = ((uint64_t)fkey(e_val[tid]) << 32) | (uint32_t)~(uint32_t)e_idx[tid];
    __syncthreads();
    if (tid < M_TOP) {
        uint64_t mine = e_pack[tid];
        uint32_t rk = 0;
        for (int j = 0; j < M_TOP; j++) rk += (e_pack[j] > mine) ? 1u : 0u;
        float mv = e_val[tid]; int mi = e_idx[tid];
        float4 l = ((const float4*)loc)[(size_t)b * N + mi];
        float4 d = ((const float4*)dbox)[mi];
        float4 bx = decode_box(l, d);
        ((float4*)cand)[(size_t)row * M_TOP + rk] = bx;   // for out_kernel gather
        s_sc[rk] = mv;
        s_bb[rk] = bx;
        s_ar[rk] = (bx.z - bx.x) * (bx.w - bx.y);
    }
    __syncthreads();

    // ---- bitmask NMS: parallel 200x200 suppression matrix (all 512 threads), ----
    // ---- then a cheap uniform greedy mask scan + compaction on wave 0.        ----
    uint64_t* sup = (uint64_t*)hist;           // hist is dead; 200*4*8B = 6.4KB
    for (int task = tid; task < M_TOP * 4; task += TK_BS) {
        int i = task >> 2, w = task & 3;
        float4 bi = s_bb[i];
        float ai = s_ar[i];
        int jb = w << 6;
        int jn = M_TOP - jb; if (jn > 64) jn = 64;
        uint64_t m = 0;
        for (int j = 0; j < jn; j++) {
            float4 bj = s_bb[jb + j];
            float xx1 = fmaxf(bi.x, bj.x);
            float yy1 = fmaxf(bi.y, bj.y);
            float xx2 = fminf(bi.z, bj.z);
            float yy2 = fminf(bi.w, bj.w);
            float inter = fmaxf(xx2 - xx1, 0.f) * fmaxf(yy2 - yy1, 0.f);
            float uni = (s_ar[jb + j] - inter) + ai;
            float iou = inter / uni;            // exact div: bit-identical to reference
            if (!(iou <= NMS_T)) m |= (1ull << j);   // NaN suppresses
        }
        sup[(i << 2) + w] = m;
    }
    __syncthreads();

    if (tid < 64) {
        int lane = tid;
        uint64_t act[4], keep[4];
        #pragma unroll
        for (int s = 0; s < 4; s++) {
            int j = (s << 6) + lane;
            float sv = (j < M_TOP) ? s_sc[j] : -1.0f;
            act[s] = __ballot(sv > CONF_T);
            keep[s] = 0;
        }
        // greedy scan: uniform across the wave (act identical in all lanes);
        // taken iterations ~= #kept, skipped ones are a 2-instr test.
        #pragma unroll
        for (int s = 0; s < 4; s++) {
            int lim = M_TOP - (s << 6); if (lim > 64) lim = 64;
            for (int bi2 = 0; bi2 < lim; bi2++) {
                if ((act[s] >> bi2) & 1ull) {
                    keep[s] |= (1ull << bi2);
                    int i4 = ((s << 6) + bi2) << 2;
                    act[0] &= ~sup[i4 + 0];
                    act[1] &= ~sup[i4 + 1];
                    act[2] &= ~sup[i4 + 2];
                    act[3] &= ~sup[i4 + 3];
                }
            }
        }
        int total = 0;
        #pragma unroll
        for (int s = 0; s < 4; s++) total += (int)__popcll(keep[s]);
        int base = 0;
        if (lane == 0 && total > 0) base = atomicAdd(&pcnt[b], total);
        base = __shfl(base, 0);
        unsigned long long lower = (lane == 0) ? 0ull : (~0ull >> (64 - lane));
        int off = base;
        #pragma unroll
        for (int s = 0; s < 4; s++) {
            if ((keep[s] >> lane) & 1ull) {
                int pos = off + (int)__popcll(keep[s] & lower);
                cmpval[(size_t)b * M + pos] = s_sc[(s << 6) + lane];
                cmpidx[(size_t)b * M + pos] = c * M_TOP + (s << 6) + lane;
            }
            off += (int)__popcll(keep[s]);
        }
    }
}

// ---------------- Kernel E: top-200 of positives -> compact (val,idx) list ----------
#define GT_BS 1024
__global__ __launch_bounds__(GT_BS) void gtop_kernel(
        const float* __restrict__ cmpval, const int* __restrict__ cmpidx,
        const int* __restrict__ pcnt, float* __restrict__ gl_val,
        int* __restrict__ gl_idx, int* __restrict__ gl_cnt, int M) {
    int b = blockIdx.x;
    int tid = threadIdx.x;
    int P = pcnt[b];
    const float* cv = cmpval + (size_t)b * M;
    const int*   ci = cmpidx + (size_t)b * M;
    if (P <= M_TOP) {
        for (int i = tid; i < P; i += GT_BS) {
            gl_val[b * M_TOP + i] = cv[i];
            gl_idx[b * M_TOP + i] = ci[i];
        }
        if (tid == 0) gl_cnt[b] = P;
        return;
    }
    __shared__ uint32_t hist[256];
    __shared__ uint32_t s_prefix, s_want;
    __shared__ int tiebuf[256];
    __shared__ uint32_t ntie, wcnt;
    __shared__ int cutoff;
    if (tid == 0) { s_prefix = 0; s_want = M_TOP; }
    for (int pass = 0; pass < 4; pass++) {
        if (tid < 256) hist[tid] = 0;
        __syncthreads();
        uint32_t prefix = s_prefix;
        int shift = 24 - 8 * pass;
        for (int i = tid; i < P; i += GT_BS) {
            uint32_t k = fkey(cv[i]);
            bool ok = (pass == 0) || ((k >> (shift + 8)) == (prefix >> (shift + 8)));
            if (ok) atomicAdd(&hist[(k >> shift) & 255u], 1u);
        }
        __syncthreads();
        if (tid == 0) {
            uint32_t want = s_want, cum = 0; int bin = 0;
            for (int bb = 255; bb >= 0; bb--) {
                if (cum + hist[bb] >= want) { bin = bb; break; }
                cum += hist[bb];
            }
            s_want = want - cum;
            s_prefix = prefix | ((uint32_t)bin << shift);
        }
        __syncthreads();
    }
    uint32_t kth = s_prefix, rfin = s_want;
    if (tid == 0) { ntie = 0; cutoff = -1; wcnt = 0; }
    __syncthreads();
    for (int i = tid; i < P; i += GT_BS) {
        if (fkey(cv[i]) == kth) { uint32_t p = atomicAdd(&ntie, 1u); if (p < 256) tiebuf[p] = ci[i]; }
    }
    __syncthreads();
    uint32_t nt = min(ntie, 256u);
    if (tid < (int)nt) {
        int mine = tiebuf[tid];
        uint32_t rk = 0;
        for (uint32_t j = 0; j < nt; j++) if (tiebuf[j] < mine) rk++;
        if (rk == rfin - 1) cutoff = mine;
    }
    __syncthreads();
    int cut = cutoff;
    for (int i = tid; i < P; i += GT_BS) {
        uint32_t k = fkey(cv[i]);
        if (k > kth || (k == kth && ci[i] <= cut)) {
            uint32_t p = atomicAdd(&wcnt, 1u);
            gl_val[b * M_TOP + p] = cv[i];
            gl_idx[b * M_TOP + p] = ci[i];
        }
    }
    if (tid == 0) gl_cnt[b] = M_TOP;
}

// ---------------- Kernel F: per-class sort + FULL output write (no memset) ----------
__global__ __launch_bounds__(256) void out_kernel(
        const float* __restrict__ gl_val, const int* __restrict__ gl_idx,
        const int* __restrict__ gl_cnt, const float* __restrict__ cand,
        float* __restrict__ out, int C, int Cm1) {
    int row = blockIdx.x;   // b*C + cc
    int b = row / C, cc = row % C;
    int tid = threadIdx.x;
    size_t oslab = (size_t)row * M_TOP * 5;
    if (cc == 0) {                         // background class: zero-fill (float4)
        float4 z; z.x = 0.f; z.y = 0.f; z.z = 0.f; z.w = 0.f;
        float4* o4 = (float4*)(out + oslab);
        for (int i = tid; i < M_TOP * 5 / 4; i += 256) o4[i] = z;
        return;
    }
    int c = cc - 1;
    __shared__ float lv[M_TOP];
    __shared__ int   lm[M_TOP];
    __shared__ uint32_t nloc;
    if (tid == 0) nloc = 0;
    __syncthreads();
    int cnt = gl_cnt[b];
    for (int i = tid; i < cnt; i += 256) {
        int idx = gl_idx[b * M_TOP + i];
        if (idx / M_TOP == c) {
            uint32_t p = atomicAdd(&nloc, 1u);
            lv[p] = gl_val[b * M_TOP + i];
            lm[p] = idx % M_TOP;
        }
    }
    __syncthreads();
    int nc = (int)nloc;
    if (tid < M_TOP) {
        if (tid < nc) {
            float v = lv[tid]; int m = lm[tid];
            int rk = 0;
            for (int j = 0; j < nc; j++)
                if (lv[j] > v || (lv[j] == v && lm[j] < m)) rk++;
            float4 bb = ((const float4*)cand)[((size_t)(b * Cm1 + c)) * M_TOP + m];
            size_t o = oslab + (size_t)rk * 5;
            out[o] = v; out[o + 1] = bb.x; out[o + 2] = bb.y;
            out[o + 3] = bb.z; out[o + 4] = bb.w;
        } else {
            size_t o = oslab + (size_t)tid * 5;
            out[o] = 0.f; out[o + 1] = 0.f; out[o + 2] = 0.f;
            out[o + 3] = 0.f; out[o + 4] = 0.f;
        }
    }
}

extern "C" void kernel_launch(void* const* d_in, const int* in_sizes, int n_in,
                              void* d_out, int out_size, void* d_ws, size_t ws_size,
                              hipStream_t stream) {
    const float* loc  = (const float*)d_in[0];
    const float* conf = (const float*)d_in[1];
    const float* dbox = (const float*)d_in[2];
    int N   = in_sizes[2] / 4;
    int B   = in_sizes[0] / (4 * N);
    int C   = in_sizes[1] / (B * N);
    int Cm1 = C - 1;
    int M   = Cm1 * M_TOP;                 // 16000 per batch

    char* ws = (char*)d_ws;
    size_t off = 0;
    auto alloc = [&](size_t bytes) -> char* {
        char* p = ws + off;
        off = (off + bytes + 255) & ~(size_t)255;
        return p;
    };
    float* sc     = (float*)alloc((size_t)B * Cm1 * N * sizeof(float));
    float* cand   = (float*)alloc((size_t)B * M * 4 * sizeof(float));
    int*   pcnt   = (int*)alloc((size_t)B * sizeof(int));
    float* cmpval = (float*)alloc((size_t)B * M * sizeof(float));
    int*   cmpidx = (int*)alloc((size_t)B * M * sizeof(int));
    float* gl_val = (float*)alloc((size_t)B * M_TOP * sizeof(float));
    int*   gl_idx = (int*)alloc((size_t)B * M_TOP * sizeof(int));
    int*   gl_cnt = (int*)alloc((size_t)B * sizeof(int));

    int bn = B * N;
    softmax_kernel<<<(bn + 255) / 256, 256, 0, stream>>>(conf, sc, pcnt, B, N, C);
    topk_kernel<<<B * Cm1, TK_BS, 0, stream>>>(sc, loc, dbox, cand, cmpval, cmpidx, pcnt,
                                               B, N, Cm1, M);
    gtop_kernel<<<B, GT_BS, 0, stream>>>(cmpval, cmpidx, pcnt, gl_val, gl_idx, gl_cnt, M);
    out_kernel<<<B * C, 256, 0, stream>>>(gl_val, gl_idx, gl_cnt, cand, (float*)d_out, C, Cm1);
}